// Round 6
// baseline (228.624 us; speedup 1.0000x reference)
//
#include <hip/hip_runtime.h>
#include <cmath>

typedef float f32x4 __attribute__((ext_vector_type(4)));
typedef float f32x16 __attribute__((ext_vector_type(16)));
typedef __bf16 bf16x8 __attribute__((ext_vector_type(8)));

#define DEV static __device__ __forceinline__

DEV unsigned short f2bf(float f) {
  unsigned int u = __builtin_bit_cast(unsigned int, f);
  u += 0x7FFFu + ((u >> 16) & 1u);
  return (unsigned short)(u >> 16);
}
DEV float bf2f(unsigned short h) {
  unsigned int u = ((unsigned int)h) << 16;
  return __builtin_bit_cast(float, u);
}
DEV unsigned int cvtpk(float lo, float hi) {  // [bf16(lo) | bf16(hi)<<16], HW RNE
  unsigned int r;
  asm("v_cvt_pk_bf16_f32 %0, %1, %2" : "=v"(r) : "v"(lo), "v"(hi));
  return r;
}
DEV f32x4 mfma16(bf16x8 a, bf16x8 b, f32x4 c) {
  return __builtin_amdgcn_mfma_f32_16x16x32_bf16(a, b, c, 0, 0, 0);
}
DEV f32x16 mfma32(bf16x8 a, bf16x8 b, f32x16 c) {
  return __builtin_amdgcn_mfma_f32_32x32x16_bf16(a, b, c, 0, 0, 0);
}
// async global->LDS, 16B per lane; lds dest = wave-uniform base (+ lane*16 by HW)
DEV void dma16(const void* g, void* l) {
  __builtin_amdgcn_global_load_lds(
      (const __attribute__((address_space(1))) void*)(uintptr_t)g,
      (__attribute__((address_space(3))) void*)(unsigned int)(uintptr_t)l,
      16, 0, 0);
}

constexpr int T_SEQ = 2048;

// ---------------------------------------------------------------- rope table
__global__ __launch_bounds__(256) void build_rope(float2* __restrict__ rope) {
  int gid = blockIdx.x * 256 + threadIdx.x;
  if (gid >= T_SEQ * 64) return;
  int t = gid >> 6, i = gid & 63;
  double inv = pow(10000.0, -((double)(2 * i)) / 128.0);
  double wl = 6.283185307179586 / inv;
  double gm = (4096.0 - wl) / (4096.0 - 128.0);
  gm = gm < 0.0 ? 0.0 : (gm > 1.0 ? 1.0 : gm);
  float f = (float)(gm * inv + (1.0 - gm) * inv * 0.25);
  float th = (float)t * f;
  float s, c;
  sincosf(th, &s, &c);
  rope[gid] = make_float2(c, s);
}

// --------------------------------- fp32 -> bf16, XOR-swizzled (2048-col rows)
__global__ __launch_bounds__(256) void cvt_f32_bf16(const float4* __restrict__ in,
                                                    ushort* __restrict__ out, int n4) {
  int i = blockIdx.x * 256 + threadIdx.x;
  if (i >= n4) return;
  float4 v = in[i];
  unsigned int lo = (unsigned int)f2bf(v.x) | ((unsigned int)f2bf(v.y) << 16);
  unsigned int hi = (unsigned int)f2bf(v.z) | ((unsigned int)f2bf(v.w) << 16);
  int row = i >> 9;                       // 512 float4 per 2048-elem row
  int e = (i * 4) & 2047;
  size_t o = ((size_t)row << 11) + (size_t)(e ^ ((row & 7) << 3));
  *(uint2*)(out + o) = make_uint2(lo, hi);
}

// --------------- fp32 RxC -> bf16 CxR transpose, XOR-swizzled output rows
__global__ __launch_bounds__(256) void tconv(const float* __restrict__ in,
                                             ushort* __restrict__ out, int R, int C) {
  __shared__ ushort tile[64][65];
  int c0 = blockIdx.x * 64, r0 = blockIdx.y * 64;
  int j = threadIdx.x & 63, i0 = threadIdx.x >> 6;
#pragma unroll
  for (int ii = 0; ii < 16; ++ii) {
    int i = i0 + ii * 4;
    tile[i][j] = f2bf(in[(size_t)(r0 + i) * C + c0 + j]);
  }
  __syncthreads();
#pragma unroll
  for (int ii = 0; ii < 16; ++ii) {
    int jr = i0 + ii * 4;
    out[(size_t)(c0 + jr) * R + ((r0 + j) ^ ((jr & 7) << 3))] = tile[j][jr];
  }
}

// ---------------- bf16 GEMM (m97 structure): C = A * Bt^T, A/Bt pre-swizzled
template <int OUT_BF16>
__global__ __launch_bounds__(256) void gemm_bt(const ushort* __restrict__ A,
                                               const ushort* __restrict__ Bt,
                                               void* __restrict__ Cv,
                                               int M, int N, int K) {
  __shared__ ushort lA[128 * 64];
  __shared__ ushort lB[128 * 64];
  const int tid = threadIdx.x;
  const int lane = tid & 63;
  const int w = tid >> 6;
  const int m0 = blockIdx.y * 128;
  const int n0 = blockIdx.x * 128;
  const int wm = (w >> 1) << 6;
  const int wn = (w & 1) << 6;

  f32x4 acc[4][4] = {};

  const size_t K2 = (size_t)K * 2;
  const char* Ab = (const char*)A + (size_t)m0 * K2;
  const char* Bb = (const char*)Bt + (size_t)n0 * K2;
  const int drow = w * 32 + (lane >> 3);
  const int dcb = (lane & 7) * 16;

  for (int k0 = 0; k0 < K; k0 += 64) {
#pragma unroll
    for (int ii = 0; ii < 4; ++ii) {
      const int off = w * 4096 + ii * 1024;
      const size_t gofs = (size_t)(drow + ii * 8) * K2 + (size_t)k0 * 2 + dcb;
      dma16(Ab + gofs, (char*)lA + off);
      dma16(Bb + gofs, (char*)lB + off);
    }
    __syncthreads();  // drains vmcnt -> DMA complete
#pragma unroll
    for (int kc = 0; kc < 2; ++kc) {
      bf16x8 a[4], bb[4];
#pragma unroll
      for (int mt = 0; mt < 4; ++mt) {
        int row = wm + mt * 16 + (lane & 15);
        int byo = kc * 64 + ((lane >> 4) << 4);
        a[mt] = *(const bf16x8*)((const char*)lA + row * 128 + (byo ^ ((row & 7) << 4)));
      }
#pragma unroll
      for (int nt = 0; nt < 4; ++nt) {
        int row = wn + nt * 16 + (lane & 15);
        int byo = kc * 64 + ((lane >> 4) << 4);
        bb[nt] = *(const bf16x8*)((const char*)lB + row * 128 + (byo ^ ((row & 7) << 4)));
      }
#pragma unroll
      for (int mt = 0; mt < 4; ++mt)
#pragma unroll
        for (int nt = 0; nt < 4; ++nt)
          acc[mt][nt] = mfma16(a[mt], bb[nt], acc[mt][nt]);
    }
    __syncthreads();
  }

  const int rr = (lane >> 4) << 2;
  const int cc = lane & 15;
  if (OUT_BF16) {
    ushort* C = (ushort*)Cv;
#pragma unroll
    for (int mt = 0; mt < 4; ++mt)
#pragma unroll
      for (int nt = 0; nt < 4; ++nt)
#pragma unroll
        for (int j = 0; j < 4; ++j) {
          int r = m0 + wm + mt * 16 + rr + j;
          int c = n0 + wn + nt * 16 + cc;
          C[(size_t)r * N + c] = f2bf(acc[mt][nt][j]);
        }
  } else {
    float* C = (float*)Cv;
#pragma unroll
    for (int mt = 0; mt < 4; ++mt)
#pragma unroll
      for (int nt = 0; nt < 4; ++nt)
#pragma unroll
        for (int j = 0; j < 4; ++j) {
          int r = m0 + wm + mt * 16 + rr + j;
          int c = n0 + wn + nt * 16 + cc;
          C[(size_t)r * N + c] = acc[mt][nt][j];
        }
  }
}

// ------------- RMSNorm + YaRN RoPE epilogue; qkv row stride 3072 (fused GEMM)
// Q additionally scaled by attn_scale * log2(e) (softmax runs in exp2 domain).
__global__ __launch_bounds__(256) void norm_rope(const ushort* __restrict__ qkv,
                                                 const float* __restrict__ qw,
                                                 const float* __restrict__ kw,
                                                 const float2* __restrict__ rope,
                                                 ushort* __restrict__ qout,
                                                 ushort* __restrict__ kout,
                                                 float q_scale) {
  const int w = threadIdx.x >> 6, lane = threadIdx.x & 63;
  const int vi = blockIdx.x * 4 + w;
  const ushort* src;
  const float* wt;
  ushort* dst;
  float extra;
  int t, bb;
  if (vi < 65536) {
    int row = vi >> 4, H = vi & 15;
    bb = row >> 11;
    t = row & 2047;
    src = qkv + (size_t)row * 3072 + H * 128 + lane * 2;
    wt = qw;
    extra = q_scale;
    dst = qout + ((size_t)(bb * 16 + H) * T_SEQ + t) * 128 + lane * 2;  // linear
  } else {
    int vi2 = vi - 65536;
    int row = vi2 >> 2, gg = vi2 & 3;
    bb = row >> 11;
    t = row & 2047;
    src = qkv + (size_t)row * 3072 + 2048 + gg * 128 + lane * 2;
    wt = kw;
    extra = 1.f;
    dst = kout + ((size_t)(bb * 4 + gg) * T_SEQ + t) * 128 +
          ((lane * 2) ^ ((t & 7) << 3));  // pre-swizzled for DMA staging
  }
  float x0 = bf2f(src[0]), x1 = bf2f(src[1]);
  float ss = x0 * x0 + x1 * x1;
#pragma unroll
  for (int d = 1; d < 64; d <<= 1) ss += __shfl_xor(ss, d, 64);
  float sc = rsqrtf(ss * (1.f / 128.f) + 1.1920929e-7f);
  float w0 = wt[lane * 2], w1 = wt[lane * 2 + 1];
  float xn0 = x0 * sc * w0, xn1 = x1 * sc * w1;
  float p0 = __shfl_xor(xn0, 32, 64), p1 = __shfl_xor(xn1, 32, 64);
  float r0 = lane < 32 ? -p0 : p0;
  float r1 = lane < 32 ? -p1 : p1;
  int i0 = (lane * 2) & 63;
  float2 cs0 = rope[t * 64 + i0];
  float2 cs1 = rope[t * 64 + i0 + 1];
  float o0 = (xn0 * cs0.x + r0 * cs0.y) * extra;
  float o1 = (xn1 * cs1.x + r1 * cs1.y) * extra;
  unsigned int pk = (unsigned int)f2bf(o0) | ((unsigned int)f2bf(o1) << 16);
  *(unsigned int*)dst = pk;
}

// ------------- V transpose: (b,t,g,d)->(b,g,d,t), pre-swizzled output rows
__global__ __launch_bounds__(256) void tv_kernel(const ushort* __restrict__ qkv,
                                                 ushort* __restrict__ vt) {
  __shared__ ushort tile[64][65];
  int t0 = blockIdx.x * 64;
  int y = blockIdx.y;  // ((b*4+g)*2 + dh)
  int dh = y & 1, bg = y >> 1;
  int bb = bg >> 2, g = bg & 3;
  int j = threadIdx.x & 63, i0 = threadIdx.x >> 6;
#pragma unroll
  for (int ii = 0; ii < 16; ++ii) {
    int i = i0 + ii * 4;
    tile[i][j] = qkv[(size_t)(bb * T_SEQ + t0 + i) * 3072 + 2560 + g * 128 + dh * 64 + j];
  }
  __syncthreads();
#pragma unroll
  for (int ii = 0; ii < 16; ++ii) {
    int jr = i0 + ii * 4;
    vt[((size_t)bg * 128 + dh * 64 + jr) * T_SEQ + ((t0 + j) ^ ((jr & 7) << 3))] = tile[j][jr];
  }
}

// P-fragment build: 4 cvt_pk + 2 permlane32_swap per kv-16-slice.
// After swap: X' = {X.lo, Y.lo}, Y' = {X.hi, Y.hi} (v_permlane32_swap_b32
// swaps vdst[32+i] <-> vsrc[i]).
#define MKPA(P, B)                                                      \
  ({                                                                    \
    unsigned X1 = cvtpk(P[B + 0], P[B + 1]);                            \
    unsigned X2 = cvtpk(P[B + 2], P[B + 3]);                            \
    unsigned Y1 = cvtpk(P[B + 4], P[B + 5]);                            \
    unsigned Y2 = cvtpk(P[B + 6], P[B + 7]);                            \
    asm("v_permlane32_swap_b32 %0, %1" : "+v"(X1), "+v"(Y1));           \
    asm("v_permlane32_swap_b32 %0, %1" : "+v"(X2), "+v"(Y2));           \
    uint4 u4 = {X1, X2, Y1, Y2};                                        \
    __builtin_bit_cast(bf16x8, u4);                                     \
  })

// ----------------------------------------------------------- flash attention
// 128-row Q-tiles, 4 waves x 32 rows/wave, 512 blocks (complement qt pairs),
// 32x32 MFMA swapped QK^T: lane owns q=lane&31, P-row fully in-lane across
// s0/s1 (kv row = (reg&3)+8*(reg>>2)+4*(lane>>5) [m74/m101], col q = lane&31).
// Softmax: in-lane tree + ONE shfl_xor(32). P -> PV A-operand in-register via
// cvt_pk + permlane32_swap (T12). No P in LDS. Double-buffered K/V DMA.
__global__ __launch_bounds__(256, 2) void attn_fwd(const ushort* __restrict__ qh,
                                                   const ushort* __restrict__ kh,
                                                   const ushort* __restrict__ vt,
                                                   ushort* __restrict__ o) {
  const int f = blockIdx.x;              // 512 blocks
  const int half = f >> 8, c = f & 255;
  const int kk = c >> 5, bh = c & 31;
  const int qt = half ? kk : (15 - kk);  // blocks c and c+256 complement, same bh
  const int b = bh >> 4, H = bh & 15;
  const int g = H & 3;
  const int tid = threadIdx.x, lane = tid & 63, w = tid >> 6;  // w in 0..3
  const int hi = lane >> 5;
  const int ql = lane & 31;
  const int wrow0 = qt * 128 + w * 32;

  __shared__ ushort lK[2][64 * 128];    // 2 x 16KB swizzled, rows = kv
  __shared__ ushort lV[2][128 * 64];    // 2 x 16KB swizzled, rows = d (V^T)

  // Q as B-operand: lane holds Q[q=ql][d = 16c + 8*hi + e], 8 slices
  bf16x8 qf[8];
  {
    const ushort* qb = qh + ((size_t)(b * 16 + H) * T_SEQ + wrow0 + ql) * 128 + 8 * hi;
#pragma unroll
    for (int cc = 0; cc < 8; ++cc) qf[cc] = *(const bf16x8*)(qb + 16 * cc);
  }

  f32x16 oacc[4] = {};                  // O[q(reg,hi)][d = 32n + ql]
  float mrow = -INFINITY, lrow = 0.f;   // per-lane: this lane's q-row stats

  const char* kpl = (const char*)(kh + (size_t)(b * 4 + g) * T_SEQ * 128);
  const char* vpl = (const char*)(vt + (size_t)(b * 4 + g) * 128 * T_SEQ);

  // per wave: 4 dma16 for K (rows 16w..16w+15) + 4 for V (d-rows 32w..32w+31)
  auto stage = [&](int j, int bi) {
#pragma unroll
    for (int ii = 0; ii < 4; ++ii) {
      const int off = w * 4096 + ii * 1024;
      dma16(kpl + (size_t)j * 16384 + off + lane * 16, (char*)lK[bi] + off);
      const int vrow = w * 32 + ii * 8 + (lane >> 3);
      dma16(vpl + (size_t)vrow * (T_SEQ * 2) + j * 128 + (lane & 7) * 16,
            (char*)lV[bi] + off);
    }
  };

  stage(0, 0);

  const int swK = (ql & 7) << 4;   // (row&7)<<4; rows ql and 32+ql share it
  const int jmax = 2 * qt + 1;

  for (int j = 0; j <= jmax; ++j) {
    const int cur = j & 1;
    if (j < jmax) {
      stage(j + 1, cur ^ 1);                            // prefetch next tile
      asm volatile("s_waitcnt vmcnt(8)" ::: "memory");  // tile j landed, j+1 in flight
    } else {
      asm volatile("s_waitcnt vmcnt(0)" ::: "memory");
    }
    __builtin_amdgcn_s_barrier();
    __builtin_amdgcn_sched_barrier(0);

    const char* lKc = (const char*)lK[cur];
    const char* lVc = (const char*)lV[cur];

    // S^T = K Q^T: A = K[kv 32-group][d], B = Q^T. D col = q = ql,
    // D row = kv = 32*grp + (reg&3) + 8*(reg>>2) + 4*hi.
    f32x16 s0 = {}, s1 = {};
    __builtin_amdgcn_s_setprio(1);
#pragma unroll
    for (int cc = 0; cc < 8; ++cc) {
      bf16x8 kf = *(const bf16x8*)(lKc + ql * 256 + ((32 * cc + 16 * hi) ^ swK));
      s0 = mfma32(kf, qf[cc], s0);
    }
#pragma unroll
    for (int cc = 0; cc < 8; ++cc) {
      bf16x8 kf = *(const bf16x8*)(lKc + (32 + ql) * 256 + ((32 * cc + 16 * hi) ^ swK));
      s1 = mfma32(kf, qf[cc], s1);
    }
    __builtin_amdgcn_s_setprio(0);

    // causal mask
    if (j * 64 + 63 > wrow0) {
      const int q = wrow0 + ql;
      const int kvb = j * 64 + 4 * hi;
#pragma unroll
      for (int r = 0; r < 16; ++r) {
        const int kv0 = kvb + (r & 3) + 8 * (r >> 2);
        if (kv0 > q) s0[r] = -3.0e38f;
        if (kv0 + 32 > q) s1[r] = -3.0e38f;
      }
    }

    // row max: in-lane tree over 32 values + one cross-half swap
    float tm[8];
#pragma unroll
    for (int r = 0; r < 8; ++r)
      tm[r] = fmaxf(fmaxf(s0[r], s0[r + 8]), fmaxf(s1[r], s1[r + 8]));
    float pm = fmaxf(fmaxf(fmaxf(tm[0], tm[1]), fmaxf(tm[2], tm[3])),
                     fmaxf(fmaxf(tm[4], tm[5]), fmaxf(tm[6], tm[7])));
    pm = fmaxf(pm, __shfl_xor(pm, 32, 64));

    float mn = mrow;
    if (!__all(pm <= mrow + 11.5417f)) {  // defer-max (exp2 domain, bound 2^11.5=e^8)
      mn = fmaxf(mrow, pm);
      float rsc = exp2f(mrow - mn);
      mrow = mn;
      lrow *= rsc;
#pragma unroll
      for (int r = 0; r < 16; ++r) {
        float rv = __shfl(rsc, (r & 3) + 8 * (r >> 2) + 4 * hi, 64);
#pragma unroll
        for (int n = 0; n < 4; ++n) oacc[n][r] *= rv;
      }
    }

    // P = exp2(S - mn); in-lane sum + one cross-half swap
    f32x16 p0, p1;
#pragma unroll
    for (int r = 0; r < 16; ++r) {
      p0[r] = exp2f(s0[r] - mn);
      p1[r] = exp2f(s1[r] - mn);
    }
    float ta[8];
#pragma unroll
    for (int r = 0; r < 8; ++r) ta[r] = (p0[r] + p0[r + 8]) + (p1[r] + p1[r + 8]);
    float ps = ((ta[0] + ta[1]) + (ta[2] + ta[3])) + ((ta[4] + ta[5]) + (ta[6] + ta[7]));
    ps += __shfl_xor(ps, 32, 64);
    lrow += ps;

    // P -> PV A-fragments, fully in-register (kv 16-slices 0..3)
    bf16x8 pa0 = MKPA(p0, 0), pa1 = MKPA(p0, 8);
    bf16x8 pa2 = MKPA(p1, 0), pa3 = MKPA(p1, 8);

    // O += P V: A = P (row q = ql, k = kv), B = V^T reads (col d = 32n + ql)
    __builtin_amdgcn_s_setprio(1);
#pragma unroll
    for (int n = 0; n < 4; ++n) {
      const int row = 32 * n + ql;
      const int swV = (row & 7) << 4;
      const char* vb = lVc + row * 128;
      bf16x8 vf0 = *(const bf16x8*)(vb + ((16 * hi) ^ swV));
      bf16x8 vf1 = *(const bf16x8*)(vb + ((32 + 16 * hi) ^ swV));
      bf16x8 vf2 = *(const bf16x8*)(vb + ((64 + 16 * hi) ^ swV));
      bf16x8 vf3 = *(const bf16x8*)(vb + ((96 + 16 * hi) ^ swV));
      oacc[n] = mfma32(pa0, vf0, oacc[n]);
      oacc[n] = mfma32(pa1, vf1, oacc[n]);
      oacc[n] = mfma32(pa2, vf2, oacc[n]);
      oacc[n] = mfma32(pa3, vf3, oacc[n]);
    }
    __builtin_amdgcn_s_setprio(0);

    __builtin_amdgcn_sched_barrier(0);
    __builtin_amdgcn_s_barrier();   // all waves done with buf[cur] before stage(j+2)
  }

  // write O (b, t, H*128+d) bf16, pre-swizzled rows for the Wo GEMM's DMA
  float linv = 1.f / lrow;
#pragma unroll
  for (int r = 0; r < 16; ++r) {
    const int qrr = (r & 3) + 8 * (r >> 2) + 4 * hi;
    float iv = __shfl(linv, qrr, 64);
    const int row = wrow0 + qrr;
    const size_t base = (size_t)(b * T_SEQ + row) * 2048;
    const int sw = (row & 7) << 3;
#pragma unroll
    for (int n = 0; n < 4; ++n) {
      int col = H * 128 + n * 32 + ql;
      o[base + (col ^ sw)] = f2bf(oacc[n][r] * iv);
    }
  }
}

// ---------------------------------------------------------------------------
extern "C" void kernel_launch(void* const* d_in, const int* in_sizes, int n_in,
                              void* d_out, int out_size, void* d_ws, size_t ws_size,
                              hipStream_t stream) {
  (void)in_sizes; (void)n_in; (void)out_size; (void)ws_size;
  const float* x = (const float*)d_in[0];
  const float* Wq = (const float*)d_in[1];
  const float* Wkv = (const float*)d_in[2];
  const float* Wo = (const float*)d_in[3];
  const float* qnw = (const float*)d_in[4];
  const float* knw = (const float*)d_in[5];
  float* out = (float*)d_out;
  char* ws = (char*)d_ws;

  ushort* xb = (ushort*)(ws);                 // 16,777,216 B (bf16 x, swizzled)
  ushort* wqkv = (ushort*)(ws + 16777216);    // 12,582,912 B (Wq^T ++ Wkv^T, swizzled)
  ushort* wot = (ushort*)(ws + 29360128);     //  8,388,608 B (Wo^T, swizzled)
  ushort* qkvraw = (ushort*)(ws + 37748736);  // 25,165,824 B (4096 x 3072, linear)
  ushort* kh = (ushort*)(ws + 62914560);      //  4,194,304 B (swizzled)
  ushort* vtp = (ushort*)(ws + 67108864);     //  4,194,304 B (swizzled)
  float2* rope = (float2*)(ws + 71303168);    //  1,048,576 B (total 72,351,744)
  ushort* qh = xb;        // alias: xb dead after projection GEMM
  ushort* attnb = qkvraw; // alias: qkvraw dead after norm_rope + tv

  float attn_scale = 1.0f / ((0.1f * logf(4.0f) + 1.0f) * sqrtf(128.0f));
  float q_scale = attn_scale * 1.44269504f;   // exp2-domain softmax

  build_rope<<<512, 256, 0, stream>>>(rope);
  cvt_f32_bf16<<<8192, 256, 0, stream>>>((const float4*)x, xb, 2097152);
  tconv<<<dim3(32, 32), 256, 0, stream>>>(Wq, wqkv, 2048, 2048);
  tconv<<<dim3(16, 32), 256, 0, stream>>>(Wkv, wqkv + (size_t)2048 * 2048, 2048, 1024);
  tconv<<<dim3(32, 32), 256, 0, stream>>>(Wo, wot, 2048, 2048);
  gemm_bt<1><<<dim3(24, 32), 256, 0, stream>>>(xb, wqkv, qkvraw, 4096, 3072, 2048);
  norm_rope<<<20480, 256, 0, stream>>>(qkvraw, qnw, knw, rope, qh, kh, q_scale);
  tv_kernel<<<dim3(32, 16), 256, 0, stream>>>(qkvraw, vtp);
  attn_fwd<<<512, 256, 0, stream>>>(qh, kh, vtp, attnb);
  gemm_bt<0><<<dim3(16, 32), 256, 0, stream>>>(attnb, wot, out, 4096, 2048, 2048);
}